// Round 1
// baseline (643.516 us; speedup 1.0000x reference)
//
#include <hip/hip_runtime.h>

#define EMBED 4096
#define NTOK 8192
#define LN_EPS 1e-5f

typedef float f4_t __attribute__((ext_vector_type(4)));
typedef __bf16 bf16x8 __attribute__((ext_vector_type(8)));
typedef unsigned short us8_t __attribute__((ext_vector_type(8)));

__device__ __forceinline__ unsigned short f2bf(float f) {
    unsigned int u = __float_as_uint(f);
    u += 0x7fffu + ((u >> 16) & 1u);   // RNE; inputs are finite
    return (unsigned short)(u >> 16);
}

typedef const __attribute__((address_space(1))) unsigned int gas_t;
typedef __attribute__((address_space(3))) unsigned int las_t;

__device__ __forceinline__ void gl_lds16(const void* g, void* l) {
    __builtin_amdgcn_global_load_lds((gas_t*)g, (las_t*)l, 16, 0, 0);
}

// ---------------- kernel 0: compact type-2 token indices -----------------
__global__ void k_compact(const int* __restrict__ types, int* __restrict__ idx,
                          int* __restrict__ counters) {
    __shared__ int cnt;
    if (threadIdx.x == 0) cnt = 0;
    __syncthreads();
    for (int i = threadIdx.x; i < NTOK; i += 1024) {
        if (types[i] == 2) {
            int s = atomicAdd(&cnt, 1);
            idx[s] = i;
        }
    }
    __syncthreads();
    if (threadIdx.x == 0) {
        counters[0] = cnt;
        counters[1] = (cnt + 127) & ~127;
    }
}

// ---------------- kernel 1: LN moment matrices ---------------------------
// aug_e = [w1_row_e , b1_e] (65-dim).  block i<65: G[i][:] = mean_e aug[i]*aug[:]
// block i==65: cbar[:] = mean_e aug[:]
__global__ __launch_bounds__(256) void k_prepG(const float* __restrict__ w1,
                                               const float* __restrict__ b1,
                                               float* __restrict__ G,
                                               float* __restrict__ cbar) {
    int i = blockIdx.x;       // 0..65
    int t = threadIdx.x;
    float part[65];
#pragma unroll
    for (int j = 0; j < 65; ++j) part[j] = 0.f;
    for (int e = t; e < EMBED; e += 256) {
        const f4_t* row4 = (const f4_t*)(w1 + (size_t)e * 64);
        float be = b1[e];
        float ai = (i < 64) ? w1[(size_t)e * 64 + i] : ((i == 64) ? be : 1.f);
#pragma unroll
        for (int q = 0; q < 16; ++q) {
            f4_t r = row4[q];
            part[4 * q + 0] += ai * r.x;
            part[4 * q + 1] += ai * r.y;
            part[4 * q + 2] += ai * r.z;
            part[4 * q + 3] += ai * r.w;
        }
        part[64] += ai * be;
    }
    // wave-level reduce, then cross-wave via LDS
#pragma unroll
    for (int j = 0; j < 65; ++j) {
        float v = part[j];
        v += __shfl_down(v, 32);
        v += __shfl_down(v, 16);
        v += __shfl_down(v, 8);
        v += __shfl_down(v, 4);
        v += __shfl_down(v, 2);
        v += __shfl_down(v, 1);
        part[j] = v;
    }
    __shared__ float sw[4][66];
    int wave = t >> 6, lane = t & 63;
    if (lane == 0) {
#pragma unroll
        for (int j = 0; j < 65; ++j) sw[wave][j] = part[j];
    }
    __syncthreads();
    if (t < 65) {
        float s = (sw[0][t] + sw[1][t] + sw[2][t] + sw[3][t]) * (1.f / 4096.f);
        if (i < 65) G[i * 65 + t] = s;
        else        cbar[t] = s;
    }
}

// ---------------- kernel 2: w2 fp32 -> bf16 ------------------------------
__global__ __launch_bounds__(256) void k_conv(const float* __restrict__ w2,
                                              unsigned short* __restrict__ w2b) {
    int i = blockIdx.x * 256 + threadIdx.x;   // handles 8 floats
    const f4_t* in4 = (const f4_t*)w2;
    f4_t v0 = in4[(size_t)i * 2];
    f4_t v1 = in4[(size_t)i * 2 + 1];
    us8_t o;
    o[0] = f2bf(v0.x); o[1] = f2bf(v0.y); o[2] = f2bf(v0.z); o[3] = f2bf(v0.w);
    o[4] = f2bf(v1.x); o[5] = f2bf(v1.y); o[6] = f2bf(v1.z); o[7] = f2bf(v1.w);
    *(us8_t*)(w2b + (size_t)i * 8) = o;
}

// ---------------- kernel 3: type 0/1 rows --------------------------------
__global__ __launch_bounds__(256) void k_enc01(const float* __restrict__ prompts,
                                               const int* __restrict__ types,
                                               const float* __restrict__ pw,
                                               const float* __restrict__ pb,
                                               const float* __restrict__ bw,
                                               const float* __restrict__ bb,
                                               const float* __restrict__ temb,
                                               float* __restrict__ out) {
    int token = blockIdx.x;
    int ty = types[token];
    if (ty >= 2) return;
    const float* x = prompts + (size_t)token * 64;
    float x0 = x[0], x1 = x[1], x2 = x[2], x3 = x[3];
    f4_t* o4 = (f4_t*)(out + (size_t)token * EMBED);
    int t = threadIdx.x;
    if (ty == 0) {
        const f4_t* w4 = (const f4_t*)pw;
        const f4_t* b4 = (const f4_t*)pb;
        const f4_t* te4 = (const f4_t*)temb;
#pragma unroll
        for (int j = 0; j < 4; ++j) {
            int e4 = t + 256 * j;
            f4_t wa = w4[e4 * 2], wb = w4[e4 * 2 + 1];
            f4_t bv = b4[e4], tv = te4[e4];
            f4_t r;
            r.x = x0 * wa.x + x1 * wa.y + bv.x + tv.x;
            r.y = x0 * wa.z + x1 * wa.w + bv.y + tv.y;
            r.z = x0 * wb.x + x1 * wb.y + bv.z + tv.z;
            r.w = x0 * wb.z + x1 * wb.w + bv.w + tv.w;
            o4[e4] = r;
        }
    } else {
        const f4_t* w4 = (const f4_t*)bw;
        const f4_t* b4 = (const f4_t*)bb;
        const f4_t* te4 = (const f4_t*)(temb + EMBED);
#pragma unroll
        for (int j = 0; j < 4; ++j) {
            int e4 = t + 256 * j;
            f4_t w0 = w4[e4 * 4 + 0], w1v = w4[e4 * 4 + 1];
            f4_t w2v = w4[e4 * 4 + 2], w3v = w4[e4 * 4 + 3];
            f4_t bv = b4[e4], tv = te4[e4];
            f4_t r;
            r.x = x0 * w0.x + x1 * w0.y + x2 * w0.z + x3 * w0.w + bv.x + tv.x;
            r.y = x0 * w1v.x + x1 * w1v.y + x2 * w1v.z + x3 * w1v.w + bv.y + tv.y;
            r.z = x0 * w2v.x + x1 * w2v.y + x2 * w2v.z + x3 * w2v.w + bv.z + tv.z;
            r.w = x0 * w3v.x + x1 * w3v.y + x2 * w3v.z + x3 * w3v.w + bv.w + tv.w;
            o4[e4] = r;
        }
    }
}

// ---------------- kernel 4: lin1 + LN + ReLU -> bf16 h -------------------
__global__ __launch_bounds__(256) void k_lin1(const float* __restrict__ prompts,
                                              const int* __restrict__ idx,
                                              const int* __restrict__ counters,
                                              const float* __restrict__ w1,
                                              const float* __restrict__ b1,
                                              const float* __restrict__ gamma,
                                              const float* __restrict__ beta,
                                              const float* __restrict__ cbar,
                                              const float* __restrict__ G,
                                              unsigned short* __restrict__ hbuf) {
    int count = counters[0], padded = counters[1];
    int base = blockIdx.x * 8;
    if (base >= padded) return;
    __shared__ __align__(16) float xs[8][68];   // 65 used, padded row stride (16B aligned)
    __shared__ float stat[8][2];
    int t = threadIdx.x;
    for (int v = t; v < 512; v += 256) {
        int r = v >> 6, k = v & 63;
        int m = base + r;
        xs[r][k] = (m < count) ? prompts[(size_t)idx[m] * 64 + k] : 0.f;
    }
    if (t < 8) xs[t][64] = (base + t < count) ? 1.f : 0.f;
    __syncthreads();
    {   // stats: 32 threads per row
        int r = t >> 5, l = t & 31;
        float mu_p = 0.f, m2_p = 0.f;
        for (int i = l; i < 65; i += 32) {
            float xi = xs[r][i];
            mu_p += cbar[i] * xi;
            const float* Gr = G + i * 65;
            float rd = 0.f;
            for (int j = 0; j < 65; ++j) rd += Gr[j] * xs[r][j];
            m2_p += xi * rd;
        }
        for (int off = 16; off > 0; off >>= 1) {
            mu_p += __shfl_down(mu_p, off, 32);
            m2_p += __shfl_down(m2_p, off, 32);
        }
        if (l == 0) {
            float var = m2_p - mu_p * mu_p;
            stat[r][0] = mu_p;
            stat[r][1] = rsqrtf(var + LN_EPS);
        }
    }
    __syncthreads();
    float mus[8], rstds[8];
    bool valid[8];
#pragma unroll
    for (int r = 0; r < 8; ++r) {
        mus[r] = stat[r][0];
        rstds[r] = stat[r][1];
        valid[r] = (base + r < count);
    }
    for (int g = 0; g < 8; ++g) {
        int e0 = t + g * 256;         // 0..2047
        int e1 = e0 + 2048;
        const f4_t* r0 = (const f4_t*)(w1 + (size_t)e0 * 64);
        const f4_t* r1 = (const f4_t*)(w1 + (size_t)e1 * 64);
        float a0[8], a1[8];
#pragma unroll
        for (int r = 0; r < 8; ++r) { a0[r] = 0.f; a1[r] = 0.f; }
#pragma unroll
        for (int kq = 0; kq < 16; ++kq) {
            f4_t w0 = r0[kq], w1q = r1[kq];
#pragma unroll
            for (int r = 0; r < 8; ++r) {
                f4_t xq = *(const f4_t*)&xs[r][kq * 4];
                a0[r] += w0.x * xq.x + w0.y * xq.y + w0.z * xq.z + w0.w * xq.w;
                a1[r] += w1q.x * xq.x + w1q.y * xq.y + w1q.z * xq.z + w1q.w * xq.w;
            }
        }
        float bv0 = b1[e0], gv0 = gamma[e0], bt0 = beta[e0];
        float bv1 = b1[e1], gv1 = gamma[e1], bt1 = beta[e1];
#pragma unroll
        for (int r = 0; r < 8; ++r) {
            size_t rowoff = (size_t)(base + r) * EMBED;
            if (valid[r]) {
                float n0 = fmaxf((a0[r] + bv0 - mus[r]) * rstds[r] * gv0 + bt0, 0.f);
                float n1 = fmaxf((a1[r] + bv1 - mus[r]) * rstds[r] * gv1 + bt1, 0.f);
                hbuf[rowoff + e0] = f2bf(n0);
                hbuf[rowoff + e1] = f2bf(n1);
            } else {
                hbuf[rowoff + e0] = 0;
                hbuf[rowoff + e1] = 0;
            }
        }
    }
}

// ---------------- kernel 5: C[m][n] = h[m]·w2[n] + b2[n] + te2[n] --------
// 128x128 tile, BK=32, 4 waves x (4x4) mfma_f32_16x16x32_bf16
__global__ __launch_bounds__(256) void k_gemm(const unsigned short* __restrict__ hbuf,
                                              const unsigned short* __restrict__ w2b,
                                              const int* __restrict__ idx,
                                              const int* __restrict__ counters,
                                              const float* __restrict__ b2,
                                              const float* __restrict__ te2,
                                              float* __restrict__ out) {
    int count = counters[0], padded = counters[1];
    int m0 = blockIdx.y * 128;
    if (m0 >= padded) return;
    int n0 = blockIdx.x * 128;

    __shared__ unsigned short At[128 * 32];   // 8 KB, [row][k] row-major
    __shared__ unsigned short Bt[128 * 32];   // 8 KB

    int t = threadIdx.x;
    int lane = t & 63, wave = t >> 6;
    int wm = (wave >> 1) * 64;   // wave's M offset in tile
    int wn = (wave & 1) * 64;    // wave's N offset in tile

    // staging: chunk c covers row=c>>2, k-group=c&3 (8 bf16 = 16B each)
    int srow = t >> 2, skg = t & 3;
    const unsigned short* Ag = hbuf + (size_t)(m0 + srow) * EMBED + skg * 8;
    const unsigned short* Bg = w2b + (size_t)(n0 + srow) * EMBED + skg * 8;
    char* AtC = (char*)At;
    char* BtC = (char*)Bt;
    int ldsw = (t & ~63) * 16;   // wave-uniform LDS byte base, call 1

    f4_t acc[4][4];
#pragma unroll
    for (int i = 0; i < 4; ++i)
#pragma unroll
        for (int j = 0; j < 4; ++j) acc[i][j] = (f4_t)0.f;

    int fr = lane & 15;          // fragment row/col within 16
    int quad = lane >> 4;

    for (int k0 = 0; k0 < EMBED; k0 += 32) {
        __syncthreads();
        gl_lds16(Ag + k0,               AtC + ldsw);
        gl_lds16(Ag + 64 * EMBED + k0,  AtC + 4096 + ldsw);
        gl_lds16(Bg + k0,               BtC + ldsw);
        gl_lds16(Bg + 64 * EMBED + k0,  BtC + 4096 + ldsw);
        __syncthreads();

        bf16x8 a[4], b[4];
#pragma unroll
        for (int i = 0; i < 4; ++i) {
            a[i] = *(const bf16x8*)(AtC + (wm + i * 16 + fr) * 64 + quad * 16);
            b[i] = *(const bf16x8*)(BtC + (wn + i * 16 + fr) * 64 + quad * 16);
        }
#pragma unroll
        for (int i = 0; i < 4; ++i)
#pragma unroll
            for (int j = 0; j < 4; ++j)
                acc[i][j] = __builtin_amdgcn_mfma_f32_16x16x32_bf16(a[i], b[j], acc[i][j], 0, 0, 0);
    }

    // epilogue: D row = quad*4 + reg, col = lane&15
#pragma unroll
    for (int i = 0; i < 4; ++i) {
#pragma unroll
        for (int r = 0; r < 4; ++r) {
            int grow = m0 + wm + i * 16 + quad * 4 + r;
            if (grow < count) {
                const float* bias = b2;
                float* orow = out + (size_t)idx[grow] * EMBED;
#pragma unroll
                for (int j = 0; j < 4; ++j) {
                    int gcol = n0 + wn + j * 16 + fr;
                    orow[gcol] = acc[i][j][r] + bias[gcol] + te2[gcol];
                }
            }
        }
    }
}

extern "C" void kernel_launch(void* const* d_in, const int* in_sizes, int n_in,
                              void* d_out, int out_size, void* d_ws, size_t ws_size,
                              hipStream_t stream) {
    const float* prompts  = (const float*)d_in[0];
    const int*   types    = (const int*)d_in[1];
    const float* point_w  = (const float*)d_in[2];
    const float* point_b  = (const float*)d_in[3];
    const float* box_w    = (const float*)d_in[4];
    const float* box_b    = (const float*)d_in[5];
    const float* poly_w1  = (const float*)d_in[6];
    const float* poly_b1  = (const float*)d_in[7];
    const float* ln_g     = (const float*)d_in[8];
    const float* ln_b     = (const float*)d_in[9];
    const float* poly_w2  = (const float*)d_in[10];
    const float* poly_b2  = (const float*)d_in[11];
    const float* type_emb = (const float*)d_in[12];
    float* out = (float*)d_out;

    char* ws = (char*)d_ws;
    int*   counters = (int*)ws;                               // 2 ints
    int*   idx      = (int*)(ws + 256);                       // 8192 ints
    float* cbar     = (float*)(ws + 33280);                   // 65 f
    float* G        = (float*)(ws + 33792);                   // 65*65 f
    unsigned short* w2b  = (unsigned short*)(ws + 65536);     // 32 MB
    unsigned short* hbuf = (unsigned short*)(ws + 65536 + (size_t)EMBED * EMBED * 2); // 64 MB

    k_compact<<<1, 1024, 0, stream>>>(types, idx, counters);
    k_prepG<<<66, 256, 0, stream>>>(poly_w1, poly_b1, G, cbar);
    k_conv<<<EMBED * EMBED / (256 * 8), 256, 0, stream>>>(poly_w2, w2b);
    k_enc01<<<NTOK, 256, 0, stream>>>(prompts, types, point_w, point_b,
                                      box_w, box_b, type_emb, out);
    k_lin1<<<NTOK / 8, 256, 0, stream>>>(prompts, idx, counters, poly_w1, poly_b1,
                                         ln_g, ln_b, cbar, G, hbuf);
    k_gemm<<<dim3(EMBED / 128, NTOK / 128), 256, 0, stream>>>(
        hbuf, w2b, idx, counters, poly_b2, type_emb + 2 * EMBED, out);
}

// Round 2
// 387.015 us; speedup vs baseline: 1.6628x; 1.6628x over previous
//
#include <hip/hip_runtime.h>

#define EMBED 4096
#define NTOK 8192
#define LN_EPS 1e-5f

typedef float f4_t __attribute__((ext_vector_type(4)));
typedef __bf16 bf16x8 __attribute__((ext_vector_type(8)));
typedef unsigned short us8_t __attribute__((ext_vector_type(8)));

__device__ __forceinline__ unsigned short f2bf(float f) {
    unsigned int u = __float_as_uint(f);
    u += 0x7fffu + ((u >> 16) & 1u);   // RNE; inputs are finite
    return (unsigned short)(u >> 16);
}

typedef const __attribute__((address_space(1))) unsigned int gas_t;
typedef __attribute__((address_space(3))) unsigned int las_t;

__device__ __forceinline__ void gl_lds16(const void* g, void* l) {
    __builtin_amdgcn_global_load_lds((gas_t*)g, (las_t*)l, 16, 0, 0);
}

// ---------------- kernel 0: compact type-2 token indices -----------------
__global__ void k_compact(const int* __restrict__ types, int* __restrict__ idx,
                          int* __restrict__ counters) {
    __shared__ int cnt;
    if (threadIdx.x == 0) cnt = 0;
    __syncthreads();
    for (int i = threadIdx.x; i < NTOK; i += 1024) {
        if (types[i] == 2) {
            int s = atomicAdd(&cnt, 1);
            idx[s] = i;
        }
    }
    __syncthreads();
    if (threadIdx.x == 0) {
        counters[0] = cnt;
        counters[1] = (cnt + 127) & ~127;
    }
}

// ---------------- kernel 1: LN moment matrices ---------------------------
// aug_e = [w1_row_e , b1_e] (65-dim).  block i<65: G[i][:] = mean_e aug[i]*aug[:]
// block i==65: cbar[:] = mean_e aug[:]
__global__ __launch_bounds__(256) void k_prepG(const float* __restrict__ w1,
                                               const float* __restrict__ b1,
                                               float* __restrict__ G,
                                               float* __restrict__ cbar) {
    int i = blockIdx.x;       // 0..65
    int t = threadIdx.x;
    float part[65];
#pragma unroll
    for (int j = 0; j < 65; ++j) part[j] = 0.f;
    for (int e = t; e < EMBED; e += 256) {
        const f4_t* row4 = (const f4_t*)(w1 + (size_t)e * 64);
        float be = b1[e];
        float ai = (i < 64) ? w1[(size_t)e * 64 + i] : ((i == 64) ? be : 1.f);
#pragma unroll
        for (int q = 0; q < 16; ++q) {
            f4_t r = row4[q];
            part[4 * q + 0] += ai * r.x;
            part[4 * q + 1] += ai * r.y;
            part[4 * q + 2] += ai * r.z;
            part[4 * q + 3] += ai * r.w;
        }
        part[64] += ai * be;
    }
#pragma unroll
    for (int j = 0; j < 65; ++j) {
        float v = part[j];
        v += __shfl_down(v, 32);
        v += __shfl_down(v, 16);
        v += __shfl_down(v, 8);
        v += __shfl_down(v, 4);
        v += __shfl_down(v, 2);
        v += __shfl_down(v, 1);
        part[j] = v;
    }
    __shared__ float sw[4][66];
    int wave = t >> 6, lane = t & 63;
    if (lane == 0) {
#pragma unroll
        for (int j = 0; j < 65; ++j) sw[wave][j] = part[j];
    }
    __syncthreads();
    if (t < 65) {
        float s = (sw[0][t] + sw[1][t] + sw[2][t] + sw[3][t]) * (1.f / 4096.f);
        if (i < 65) G[i * 65 + t] = s;
        else        cbar[t] = s;
    }
}

// ---------------- kernel 2: fp32 -> bf16 cast (generic, 8 elems/thread) --
__global__ __launch_bounds__(256) void k_conv(const float* __restrict__ src,
                                              unsigned short* __restrict__ dst) {
    int i = blockIdx.x * 256 + threadIdx.x;   // handles 8 floats
    const f4_t* in4 = (const f4_t*)src;
    f4_t v0 = in4[(size_t)i * 2];
    f4_t v1 = in4[(size_t)i * 2 + 1];
    us8_t o;
    o[0] = f2bf(v0.x); o[1] = f2bf(v0.y); o[2] = f2bf(v0.z); o[3] = f2bf(v0.w);
    o[4] = f2bf(v1.x); o[5] = f2bf(v1.y); o[6] = f2bf(v1.z); o[7] = f2bf(v1.w);
    *(us8_t*)(dst + (size_t)i * 8) = o;
}

// ---------------- kernel 3: type 0/1 rows --------------------------------
__global__ __launch_bounds__(256) void k_enc01(const float* __restrict__ prompts,
                                               const int* __restrict__ types,
                                               const float* __restrict__ pw,
                                               const float* __restrict__ pb,
                                               const float* __restrict__ bw,
                                               const float* __restrict__ bb,
                                               const float* __restrict__ temb,
                                               float* __restrict__ out) {
    int token = blockIdx.x;
    int ty = types[token];
    if (ty >= 2) return;
    const float* x = prompts + (size_t)token * 64;
    float x0 = x[0], x1 = x[1], x2 = x[2], x3 = x[3];
    f4_t* o4 = (f4_t*)(out + (size_t)token * EMBED);
    int t = threadIdx.x;
    if (ty == 0) {
        const f4_t* w4 = (const f4_t*)pw;
        const f4_t* b4 = (const f4_t*)pb;
        const f4_t* te4 = (const f4_t*)temb;
#pragma unroll
        for (int j = 0; j < 4; ++j) {
            int e4 = t + 256 * j;
            f4_t wa = w4[e4 * 2], wb = w4[e4 * 2 + 1];
            f4_t bv = b4[e4], tv = te4[e4];
            f4_t r;
            r.x = x0 * wa.x + x1 * wa.y + bv.x + tv.x;
            r.y = x0 * wa.z + x1 * wa.w + bv.y + tv.y;
            r.z = x0 * wb.x + x1 * wb.y + bv.z + tv.z;
            r.w = x0 * wb.z + x1 * wb.w + bv.w + tv.w;
            o4[e4] = r;
        }
    } else {
        const f4_t* w4 = (const f4_t*)bw;
        const f4_t* b4 = (const f4_t*)bb;
        const f4_t* te4 = (const f4_t*)(temb + EMBED);
#pragma unroll
        for (int j = 0; j < 4; ++j) {
            int e4 = t + 256 * j;
            f4_t w0 = w4[e4 * 4 + 0], w1v = w4[e4 * 4 + 1];
            f4_t w2v = w4[e4 * 4 + 2], w3v = w4[e4 * 4 + 3];
            f4_t bv = b4[e4], tv = te4[e4];
            f4_t r;
            r.x = x0 * w0.x + x1 * w0.y + x2 * w0.z + x3 * w0.w + bv.x + tv.x;
            r.y = x0 * w1v.x + x1 * w1v.y + x2 * w1v.z + x3 * w1v.w + bv.y + tv.y;
            r.z = x0 * w2v.x + x1 * w2v.y + x2 * w2v.z + x3 * w2v.w + bv.z + tv.z;
            r.w = x0 * w3v.x + x1 * w3v.y + x2 * w3v.z + x3 * w3v.w + bv.w + tv.w;
            o4[e4] = r;
        }
    }
}

// ---------------- kernel 4: LN stats per type-2 row + bf16 x gather ------
// mu = cbar . x'   E[h^2] = x'^T G x'   (x' = [x,1], 65-dim), fp32-exact.
// Also emits xbuf (padded x 64, bf16, zero-padded rows).
__global__ __launch_bounds__(256) void k_stats(const float* __restrict__ prompts,
                                               const int* __restrict__ idx,
                                               const int* __restrict__ counters,
                                               const float* __restrict__ cbar,
                                               const float* __restrict__ G,
                                               float* __restrict__ mu,
                                               float* __restrict__ rstd,
                                               unsigned short* __restrict__ xbuf) {
    int count = counters[0], padded = counters[1];
    int base = blockIdx.x * 4;
    if (base >= padded) return;
    __shared__ float sG[65 * 65];
    __shared__ __align__(16) float xs[4][66];
    int t = threadIdx.x;
    for (int v = t; v < 65 * 65; v += 256) sG[v] = G[v];
    int r = t >> 6, lane = t & 63;
    int m = base + r;
    bool vld = (m < count);
    float xv = vld ? prompts[(size_t)idx[m] * 64 + lane] : 0.f;
    xs[r][lane] = xv;
    if (lane == 0) xs[r][64] = vld ? 1.f : 0.f;
    xbuf[(size_t)m * 64 + lane] = vld ? f2bf(xv) : (unsigned short)0;
    __syncthreads();
    float mu_p, m2_p;
    {
        float xi = xs[r][lane];
        mu_p = cbar[lane] * xi;
        const float* Gr = sG + lane * 65;
        float rd = 0.f;
        for (int j = 0; j < 65; ++j) rd += Gr[j] * xs[r][j];
        m2_p = xi * rd;
    }
    if (lane == 0) {   // i = 64 term
        float xi = xs[r][64];
        mu_p += cbar[64] * xi;
        const float* Gr = sG + 64 * 65;
        float rd = 0.f;
        for (int j = 0; j < 65; ++j) rd += Gr[j] * xs[r][j];
        m2_p += xi * rd;
    }
    for (int off = 32; off > 0; off >>= 1) {
        mu_p += __shfl_down(mu_p, off);
        m2_p += __shfl_down(m2_p, off);
    }
    if (lane == 0) {
        if (vld) {
            mu[m] = mu_p;
            rstd[m] = rsqrtf(fmaxf(m2_p - mu_p * mu_p, 0.f) + LN_EPS);
        } else {
            mu[m] = 0.f;
            rstd[m] = 0.f;
        }
    }
}

// ---------------- kernel 5: lin1 as MFMA GEMM, fused LN+ReLU -> hbuf -----
// A = xbuf [padded x 64] bf16, B = w1b [4096 x 64] bf16 (N x K row-major)
__global__ __launch_bounds__(256) void k_lin1m(const unsigned short* __restrict__ xbuf,
                                               const unsigned short* __restrict__ w1b,
                                               const int* __restrict__ counters,
                                               const float* __restrict__ b1,
                                               const float* __restrict__ gamma,
                                               const float* __restrict__ beta,
                                               const float* __restrict__ mu,
                                               const float* __restrict__ rstd,
                                               unsigned short* __restrict__ hbuf) {
    int padded = counters[1];
    int m0 = blockIdx.y * 128;
    if (m0 >= padded) return;
    int n0 = blockIdx.x * 128;

    __shared__ unsigned short At[128 * 32];
    __shared__ unsigned short Bt[128 * 32];

    int t = threadIdx.x;
    int lane = t & 63, wave = t >> 6;
    int wm = (wave >> 1) * 64;
    int wn = (wave & 1) * 64;

    int srow = t >> 2, skg = t & 3;
    const unsigned short* Ag = xbuf + (size_t)(m0 + srow) * 64 + skg * 8;
    const unsigned short* Bg = w1b + (size_t)(n0 + srow) * 64 + skg * 8;
    char* AtC = (char*)At;
    char* BtC = (char*)Bt;
    int ldsw = (t & ~63) * 16;

    f4_t acc[4][4];
#pragma unroll
    for (int i = 0; i < 4; ++i)
#pragma unroll
        for (int j = 0; j < 4; ++j) acc[i][j] = (f4_t)0.f;

    int fr = lane & 15;
    int quad = lane >> 4;

#pragma unroll
    for (int k0 = 0; k0 < 64; k0 += 32) {
        __syncthreads();
        gl_lds16(Ag + k0,            AtC + ldsw);
        gl_lds16(Ag + 64 * 64 + k0,  AtC + 4096 + ldsw);
        gl_lds16(Bg + k0,            BtC + ldsw);
        gl_lds16(Bg + 64 * 64 + k0,  BtC + 4096 + ldsw);
        __syncthreads();

        bf16x8 a[4], b[4];
#pragma unroll
        for (int i = 0; i < 4; ++i) {
            a[i] = *(const bf16x8*)(AtC + (wm + i * 16 + fr) * 64 + quad * 16);
            b[i] = *(const bf16x8*)(BtC + (wn + i * 16 + fr) * 64 + quad * 16);
        }
#pragma unroll
        for (int i = 0; i < 4; ++i)
#pragma unroll
            for (int j = 0; j < 4; ++j)
                acc[i][j] = __builtin_amdgcn_mfma_f32_16x16x32_bf16(a[i], b[j], acc[i][j], 0, 0, 0);
    }

#pragma unroll
    for (int i = 0; i < 4; ++i) {
#pragma unroll
        for (int r = 0; r < 4; ++r) {
            int grow = m0 + wm + i * 16 + quad * 4 + r;   // always < padded
            float muv = mu[grow], rsv = rstd[grow];
            unsigned short* hrow = hbuf + (size_t)grow * EMBED;
#pragma unroll
            for (int j = 0; j < 4; ++j) {
                int gcol = n0 + wn + j * 16 + fr;
                float h = (acc[i][j][r] + b1[gcol] - muv) * rsv * gamma[gcol] + beta[gcol];
                hrow[gcol] = f2bf(fmaxf(h, 0.f));
            }
        }
    }
}

// ---------------- kernel 6: C[m][n] = h[m].w2[n] + b2[n] + te2[n] --------
__global__ __launch_bounds__(256) void k_gemm(const unsigned short* __restrict__ hbuf,
                                              const unsigned short* __restrict__ w2b,
                                              const int* __restrict__ idx,
                                              const int* __restrict__ counters,
                                              const float* __restrict__ b2,
                                              const float* __restrict__ te2,
                                              float* __restrict__ out) {
    int count = counters[0], padded = counters[1];
    int m0 = blockIdx.y * 128;
    if (m0 >= padded) return;
    int n0 = blockIdx.x * 128;

    __shared__ unsigned short At[128 * 32];
    __shared__ unsigned short Bt[128 * 32];

    int t = threadIdx.x;
    int lane = t & 63, wave = t >> 6;
    int wm = (wave >> 1) * 64;
    int wn = (wave & 1) * 64;

    int srow = t >> 2, skg = t & 3;
    const unsigned short* Ag = hbuf + (size_t)(m0 + srow) * EMBED + skg * 8;
    const unsigned short* Bg = w2b + (size_t)(n0 + srow) * EMBED + skg * 8;
    char* AtC = (char*)At;
    char* BtC = (char*)Bt;
    int ldsw = (t & ~63) * 16;

    f4_t acc[4][4];
#pragma unroll
    for (int i = 0; i < 4; ++i)
#pragma unroll
        for (int j = 0; j < 4; ++j) acc[i][j] = (f4_t)0.f;

    int fr = lane & 15;
    int quad = lane >> 4;

    for (int k0 = 0; k0 < EMBED; k0 += 32) {
        __syncthreads();
        gl_lds16(Ag + k0,               AtC + ldsw);
        gl_lds16(Ag + 64 * EMBED + k0,  AtC + 4096 + ldsw);
        gl_lds16(Bg + k0,               BtC + ldsw);
        gl_lds16(Bg + 64 * EMBED + k0,  BtC + 4096 + ldsw);
        __syncthreads();

        bf16x8 a[4], b[4];
#pragma unroll
        for (int i = 0; i < 4; ++i) {
            a[i] = *(const bf16x8*)(AtC + (wm + i * 16 + fr) * 64 + quad * 16);
            b[i] = *(const bf16x8*)(BtC + (wn + i * 16 + fr) * 64 + quad * 16);
        }
#pragma unroll
        for (int i = 0; i < 4; ++i)
#pragma unroll
            for (int j = 0; j < 4; ++j)
                acc[i][j] = __builtin_amdgcn_mfma_f32_16x16x32_bf16(a[i], b[j], acc[i][j], 0, 0, 0);
    }

#pragma unroll
    for (int i = 0; i < 4; ++i) {
#pragma unroll
        for (int r = 0; r < 4; ++r) {
            int grow = m0 + wm + i * 16 + quad * 4 + r;
            if (grow < count) {
                float* orow = out + (size_t)idx[grow] * EMBED;
#pragma unroll
                for (int j = 0; j < 4; ++j) {
                    int gcol = n0 + wn + j * 16 + fr;
                    orow[gcol] = acc[i][j][r] + b2[gcol] + te2[gcol];
                }
            }
        }
    }
}

extern "C" void kernel_launch(void* const* d_in, const int* in_sizes, int n_in,
                              void* d_out, int out_size, void* d_ws, size_t ws_size,
                              hipStream_t stream) {
    const float* prompts  = (const float*)d_in[0];
    const int*   types    = (const int*)d_in[1];
    const float* point_w  = (const float*)d_in[2];
    const float* point_b  = (const float*)d_in[3];
    const float* box_w    = (const float*)d_in[4];
    const float* box_b    = (const float*)d_in[5];
    const float* poly_w1  = (const float*)d_in[6];
    const float* poly_b1  = (const float*)d_in[7];
    const float* ln_g     = (const float*)d_in[8];
    const float* ln_b     = (const float*)d_in[9];
    const float* poly_w2  = (const float*)d_in[10];
    const float* poly_b2  = (const float*)d_in[11];
    const float* type_emb = (const float*)d_in[12];
    float* out = (float*)d_out;

    char* ws = (char*)d_ws;
    int*   counters = (int*)ws;                               // 2 ints
    int*   idx      = (int*)(ws + 256);                       // 8192 ints
    float* cbar     = (float*)(ws + 33280);                   // 65 f
    float* G        = (float*)(ws + 33792);                   // 65*65 f -> ends 50692
    float* muarr    = (float*)(ws + 51200);                   // 8192 f
    float* rstdarr  = (float*)(ws + 84224);                   // 8192 f
    unsigned short* xbuf = (unsigned short*)(ws + 131072);    // 1 MB
    unsigned short* w1b  = (unsigned short*)(ws + 131072 + 1048576);  // 512 KB
    unsigned short* w2b  = (unsigned short*)(ws + 2097152);   // 32 MB
    unsigned short* hbuf = (unsigned short*)(ws + 2097152 + (size_t)EMBED * EMBED * 2); // 64 MB

    k_compact<<<1, 1024, 0, stream>>>(types, idx, counters);
    k_prepG<<<66, 256, 0, stream>>>(poly_w1, poly_b1, G, cbar);
    k_conv<<<EMBED * EMBED / (256 * 8), 256, 0, stream>>>(poly_w2, w2b);
    k_conv<<<EMBED * 64 / (256 * 8), 256, 0, stream>>>(poly_w1, w1b);
    k_enc01<<<NTOK, 256, 0, stream>>>(prompts, types, point_w, point_b,
                                      box_w, box_b, type_emb, out);
    k_stats<<<NTOK / 4, 256, 0, stream>>>(prompts, idx, counters, cbar, G,
                                          muarr, rstdarr, xbuf);
    k_lin1m<<<dim3(EMBED / 128, NTOK / 128), 256, 0, stream>>>(
        xbuf, w1b, counters, poly_b1, ln_g, ln_b, muarr, rstdarr, hbuf);
    k_gemm<<<dim3(EMBED / 128, NTOK / 128), 256, 0, stream>>>(
        hbuf, w2b, idx, counters, poly_b2, type_emb + 2 * EMBED, out);
}